// Round 5
// baseline (232.405 us; speedup 1.0000x reference)
//
#include <hip/hip_runtime.h>
#include <hip/hip_bf16.h>

#define DEPTH   6
#define NLEAF   64
#define BATCH   1024
#define DIM     256
#define NTREES  512
#define UNITS   16
#define NCOLS   (NTREES*DEPTH)          // 3072

// ================= primary path (needs ~21 MB ws) =================
// ---- GEMM tile: 64x64, 128 threads, micro 4 rows x 8 cols, KCH=32 ----
#define TM    64
#define TN    64
#define KCH   32
#define APAD  36                         // la[row][k] stride
#define BPAD  68                         // lb[k][col] stride
#define MB    (BATCH/TM)                 // 16
#define NB    (NCOLS/TN)                 // 48

// ---- tree kernel ----
#define TPT   4                          // trees per thread
#define NTG   (NTREES/TPT)               // 128

// primary ws layout (floats):
//   gates   : BATCH*NCOLS = 3145728 (12.6 MB)
//   thrp    : NCOLS       = 3072
//   shared  : max(selp 786432, partial NTG*BATCH*UNITS = 2097152)
#define WS_GATES 0
#define WS_THRP  (WS_GATES + BATCH*NCOLS)
#define WS_SH    (WS_THRP + NCOLS)
#define WS_PRIMARY_FLOATS (WS_SH + NTG*BATCH*UNITS)   // 5245952 (~21 MB)

// fallback ws layout (floats) — round-2 proven footprint (~7.35 MB):
#define FB_SELP    0
#define FB_THRP    (FB_SELP + DIM*NTREES*DEPTH)       // 786432
#define FB_PARTIAL (FB_THRP + NCOLS)                  // 789504
#define FBT   8                          // trees per fused block
#define FBB   128                        // batch rows per fused block
#define FBK   32
#define FBNT  (NTREES/FBT)               // 64
#define FBBB  (BATCH/FBB)                // 8
#define FBND  (FBT*DEPTH)                // 48

// ---------------------------------------------------------------------------
// prep: sparsemax over depth axis of (dim, n_trees, depth), scaled by
// exp(-log_temp); tail block computes thrp = thr * exp(-log_temp).
// ---------------------------------------------------------------------------
__global__ void prep_kernel(const float* __restrict__ fsl,
                            const float* __restrict__ thr,
                            const float* __restrict__ lt,
                            float* __restrict__ selp,
                            float* __restrict__ thrp) {
    if (blockIdx.x == (DIM * NTREES) / 256) {          // tail: thrp
        for (int j = threadIdx.x; j < NCOLS; j += 256)
            thrp[j] = thr[j] * __expf(-lt[j]);
        return;
    }
    int t = blockIdx.x * 256 + threadIdx.x;            // t = i*NTREES + n
    int n = t & (NTREES - 1);
    int base = t * DEPTH;

    float zv[DEPTH], zs[DEPTH];
#pragma unroll
    for (int d = 0; d < DEPTH; ++d) { zv[d] = fsl[base + d]; zs[d] = zv[d]; }

#pragma unroll
    for (int p = 0; p < DEPTH - 1; ++p)
#pragma unroll
        for (int j = 0; j < DEPTH - 1 - p; ++j) {
            float a = zs[j], b = zs[j + 1];
            zs[j] = fmaxf(a, b); zs[j + 1] = fminf(a, b);
        }

    float cs[DEPTH];
    cs[0] = zs[0];
#pragma unroll
    for (int d = 1; d < DEPTH; ++d) cs[d] = cs[d - 1] + zs[d];

    int k = 0;
#pragma unroll
    for (int d = 0; d < DEPTH; ++d)
        if (zs[d] * (float)(d + 1) > cs[d] - 1.0f) k++;

    float csk = cs[0];
#pragma unroll
    for (int d = 0; d < DEPTH; ++d) csk = (k - 1 == d) ? cs[d] : csk;
    float tau = (csk - 1.0f) / (float)k;

#pragma unroll
    for (int d = 0; d < DEPTH; ++d) {
        float it = __expf(-lt[n * DEPTH + d]);
        selp[base + d] = fmaxf(zv[d] - tau, 0.0f) * it;
    }
}

// ---------------------------------------------------------------------------
// gemm_gates: gates = sparsemoid( x(1024x256) @ selp(256x3072) - thrp )
// 64x64 tile, 128 threads (micro 4x8), KCH=32, register prefetch (T14).
// LDS bytes/FMA = 1.5; all staged/computed accesses <=2-way bank aliasing.
// ---------------------------------------------------------------------------
__global__ __launch_bounds__(128)
void gemm_gates(const float* __restrict__ x,
                const float* __restrict__ selp,
                const float* __restrict__ thrp,
                float* __restrict__ gates) {
    __shared__ float la[TM * APAD];      // [row][k]
    __shared__ float lb[KCH * BPAD];     // [k][col]

    const int tid = threadIdx.x;
    const int n0  = blockIdx.x * TN;
    const int m0  = blockIdx.y * TM;
    const int tx  = tid & 7;             // col group (8 cols)
    const int ty  = tid >> 3;            // row group (4 rows), 0..15

    float acc[4][8];
#pragma unroll
    for (int r = 0; r < 4; ++r)
#pragma unroll
        for (int c = 0; c < 8; ++c) acc[r][c] = 0.0f;

    float4 ra[4], rb[4];
    int ar[4], ak[4], bk[4], bc_[4];
#pragma unroll
    for (int i = 0; i < 4; ++i) {
        int e = tid + i * 128;           // 0..511
        ar[i] = e >> 3;  ak[i] = e & 7;  // A: row, k-group(4)
        bk[i] = e >> 4;  bc_[i] = e & 15;// B: k, col-group(4)
    }

#define STAGE(KC_)                                                            \
    _Pragma("unroll")                                                         \
    for (int i = 0; i < 4; ++i) {                                             \
        ra[i] = *(const float4*)&x[(m0 + ar[i]) * DIM + (KC_) * KCH + ak[i] * 4]; \
        rb[i] = *(const float4*)&selp[((KC_) * KCH + bk[i]) * NCOLS + n0 + bc_[i] * 4]; \
    }
#define COMMIT()                                                              \
    _Pragma("unroll")                                                         \
    for (int i = 0; i < 4; ++i) {                                             \
        *(float4*)&la[ar[i] * APAD + ak[i] * 4] = ra[i];                      \
        *(float4*)&lb[bk[i] * BPAD + bc_[i] * 4] = rb[i];                     \
    }

    STAGE(0)
    COMMIT()
    __syncthreads();

    const int NKC = DIM / KCH;           // 8
    for (int kc = 0; kc < NKC; ++kc) {
        if (kc < NKC - 1) STAGE(kc + 1)  // issue-early; vmcnt waits land in COMMIT

#pragma unroll
        for (int kk = 0; kk < KCH; kk += 4) {
            float a4[4][4];
#pragma unroll
            for (int r = 0; r < 4; ++r)
                *(float4*)a4[r] = *(const float4*)&la[(ty * 4 + r) * APAD + kk];
            float b4[4][8];
#pragma unroll
            for (int j = 0; j < 4; ++j) {
                *(float4*)&b4[j][0] = *(const float4*)&lb[(kk + j) * BPAD + tx * 8];
                *(float4*)&b4[j][4] = *(const float4*)&lb[(kk + j) * BPAD + tx * 8 + 4];
            }
#pragma unroll
            for (int j = 0; j < 4; ++j)
#pragma unroll
                for (int r = 0; r < 4; ++r)
#pragma unroll
                    for (int c = 0; c < 8; ++c)
                        acc[r][c] = fmaf(a4[r][j], b4[j][c], acc[r][c]);
        }

        if (kc < NKC - 1) {
            __syncthreads();
            COMMIT()
            __syncthreads();
        }
    }
#undef STAGE
#undef COMMIT

    // epilogue: sparsemoid + store (cols n0+tx*8 .. +7)
    float th[8];
    *(float4*)&th[0] = *(const float4*)&thrp[n0 + tx * 8];
    *(float4*)&th[4] = *(const float4*)&thrp[n0 + tx * 8 + 4];
#pragma unroll
    for (int r = 0; r < 4; ++r) {
        float o[8];
#pragma unroll
        for (int c = 0; c < 8; ++c) {
            float tl = acc[r][c] - th[c];
            o[c] = fminf(fmaxf(fmaf(0.5f, tl, 0.5f), 0.0f), 1.0f);
        }
        float* gp = &gates[(size_t)(m0 + ty * 4 + r) * NCOLS + n0 + tx * 8];
        *(float4*)&gp[0] = *(float4*)&o[0];
        *(float4*)&gp[4] = *(float4*)&o[4];
    }
}

// ---------------------------------------------------------------------------
// tree_kernel: pure-register, no LDS/barriers. Flat 1024-block grid,
// bc = bid&7 matches XCD round-robin -> per-XCD gates slice (1.5 MB) + resp
// (2 MB) fit the 4 MB per-XCD L2.
// ---------------------------------------------------------------------------
__global__ __launch_bounds__(256)
void tree_kernel(const float* __restrict__ gates,
                 const float* __restrict__ resp,
                 float* __restrict__ partial) {
    const int bid  = blockIdx.x;
    const int bc   = bid & 7;                          // batch slice (XCD-pinned)
    const int tg   = bid >> 3;                         // tree group 0..127
    const int tid  = threadIdx.x;
    const int lane = tid & 63;
    const int uh   = __builtin_amdgcn_readfirstlane((tid >> 6) & 1);
    const int b    = bc * 128 + (tid >> 7) * 64 + lane;

    float g[TPT * DEPTH];
    const float* gp = gates + (size_t)b * NCOLS + tg * (TPT * DEPTH);
#pragma unroll
    for (int i = 0; i < 6; ++i)
        *(float4*)&g[i * 4] = *(const float4*)&gp[i * 4];

    float out8[8];
#pragma unroll
    for (int u = 0; u < 8; ++u) out8[u] = 0.0f;

#pragma unroll
    for (int t = 0; t < TPT; ++t) {
        float p[NLEAF];
        p[0] = 1.0f;
#pragma unroll
        for (int d = 0; d < DEPTH; ++d) {
            int w = 1 << d;
            float gd = g[t * DEPTH + d], hd = 1.0f - gd;
#pragma unroll
            for (int c = w - 1; c >= 0; --c) {
                float base = p[c];
                p[c + w] = base * hd;
                p[c]     = base * gd;
            }
        }
        const float* rp = resp + (size_t)((tg * TPT + t) * UNITS + uh * 8) * NLEAF;
#pragma unroll
        for (int u = 0; u < 8; ++u) {
            float a = 0.0f;
#pragma unroll
            for (int c = 0; c < NLEAF; ++c)
                a = fmaf(p[c], rp[u * NLEAF + c], a);
            out8[u] += a;
        }
    }

    float* pp = partial + ((size_t)tg * BATCH + b) * UNITS + uh * 8;
    *(float4*)&pp[0] = *(float4*)&out8[0];
    *(float4*)&pp[4] = *(float4*)&out8[4];
}

// ---------------------------------------------------------------------------
// reduce over nt partials, scale 1/NTREES (shared by both paths)
// ---------------------------------------------------------------------------
__global__ void reduce_kernel(const float* __restrict__ partial,
                              float* __restrict__ out, int nt) {
    int idx = blockIdx.x * 256 + threadIdx.x;          // 0..16383
    float s = 0.0f;
    for (int tg = 0; tg < nt; ++tg)
        s += partial[(size_t)tg * BATCH * UNITS + idx];
    out[idx] = s * (1.0f / (float)NTREES);
}

// ---------------------------------------------------------------------------
// FALLBACK: round-2 proven fused kernel (used only if ws_size < 21 MB)
// ---------------------------------------------------------------------------
__global__ __launch_bounds__(256)
void fused_kernel(const float* __restrict__ x,
                  const float* __restrict__ selp,
                  const float* __restrict__ thrp,
                  const float* __restrict__ resp,
                  float* __restrict__ partial) {
    __shared__ union SM {
        struct {
            float x[FBK][132];
            float sel[FBK][FBT * 8];
        } a;
        float gates[FBND][FBB];
    } sm;

    const int tid   = threadIdx.x;
    const int ntile = blockIdx.x;
    const int btile = blockIdx.y;
    const int b0    = btile * FBB;
    const int col0  = ntile * FBND;
    const int ng0   = ntile * FBT;

    const int tn = tid & (FBT - 1);
    const int tb = tid >> 3;

    float acc[4][DEPTH];
#pragma unroll
    for (int bb = 0; bb < 4; ++bb)
#pragma unroll
        for (int d = 0; d < DEPTH; ++d) acc[bb][d] = 0.0f;

    for (int kc = 0; kc < DIM; kc += FBK) {
#pragma unroll
        for (int i = 0; i < 16; ++i) {
            int e = tid + i * 256;
            int b = e >> 5;
            int k = e & 31;
            sm.a.x[k][b] = x[(b0 + b) * DIM + kc + k];
        }
#pragma unroll
        for (int i = 0; i < 6; ++i) {
            int e = tid + i * 256;
            int k = e / FBND;
            int c = e - k * FBND;
            int tt = c / DEPTH;
            int d  = c - tt * DEPTH;
            sm.a.sel[k][tt * 8 + d] = selp[(kc + k) * NCOLS + col0 + c];
        }
        __syncthreads();

#pragma unroll 8
        for (int k = 0; k < FBK; ++k) {
            float4 xv = *(const float4*)&sm.a.x[k][tb * 4];
            float4 s0 = *(const float4*)&sm.a.sel[k][tn * 8];
            float2 s1 = *(const float2*)&sm.a.sel[k][tn * 8 + 4];
            float xb[4] = {xv.x, xv.y, xv.z, xv.w};
            float sv[DEPTH] = {s0.x, s0.y, s0.z, s0.w, s1.x, s1.y};
#pragma unroll
            for (int bb = 0; bb < 4; ++bb)
#pragma unroll
                for (int d = 0; d < DEPTH; ++d)
                    acc[bb][d] = fmaf(xb[bb], sv[d], acc[bb][d]);
        }
        __syncthreads();
    }

#pragma unroll
    for (int d = 0; d < DEPTH; ++d) {
        float th = thrp[(ng0 + tn) * DEPTH + d];
#pragma unroll
        for (int bb = 0; bb < 4; ++bb) {
            float tl = acc[bb][d] - th;
            float g  = fminf(fmaxf(0.5f * tl + 0.5f, 0.0f), 1.0f);
            sm.gates[tn * DEPTH + d][tb * 4 + bb] = g;
        }
    }
    __syncthreads();

    const int b  = tid & (FBB - 1);
    const int uh = __builtin_amdgcn_readfirstlane(tid >> 7);

    float out8[8];
#pragma unroll
    for (int u = 0; u < 8; ++u) out8[u] = 0.0f;

    for (int n = 0; n < FBT; ++n) {
        float g[DEPTH];
#pragma unroll
        for (int d = 0; d < DEPTH; ++d) g[d] = sm.gates[n * DEPTH + d][b];

        float p[NLEAF];
        p[0] = 1.0f;
#pragma unroll
        for (int d = 0; d < DEPTH; ++d) {
            int w = 1 << d;
            float gd = g[d], hd = 1.0f - g[d];
#pragma unroll
            for (int c = w - 1; c >= 0; --c) {
                float base = p[c];
                p[c + w] = base * hd;
                p[c]     = base * gd;
            }
        }

        const float* rp = resp + (((ng0 + n) * UNITS) + uh * 8) * NLEAF;
#pragma unroll
        for (int u = 0; u < 8; ++u) {
            float a = 0.0f;
#pragma unroll
            for (int c = 0; c < NLEAF; ++c)
                a = fmaf(p[c], rp[u * NLEAF + c], a);
            out8[u] += a;
        }
    }

    float* pp = partial + ((size_t)(ntile * BATCH + b0 + b)) * UNITS + uh * 8;
    *(float4*)&pp[0] = *(float4*)&out8[0];
    *(float4*)&pp[4] = *(float4*)&out8[4];
}

// ---------------------------------------------------------------------------
extern "C" void kernel_launch(void* const* d_in, const int* in_sizes, int n_in,
                              void* d_out, int out_size, void* d_ws, size_t ws_size,
                              hipStream_t stream) {
    const float* x    = (const float*)d_in[0];
    const float* fsl  = (const float*)d_in[1];
    const float* thr  = (const float*)d_in[2];
    const float* lt   = (const float*)d_in[3];
    const float* resp = (const float*)d_in[4];
    float* out = (float*)d_out;
    float* ws  = (float*)d_ws;

    if (ws_size >= (size_t)WS_PRIMARY_FLOATS * sizeof(float)) {
        // ---------- primary: split pipeline (~21 MB ws) ----------
        float* gates   = ws + WS_GATES;
        float* thrp    = ws + WS_THRP;
        float* selp    = ws + WS_SH;     // lifetime: prep -> gemm
        float* partial = ws + WS_SH;     // lifetime: tree -> reduce (overlay)

        prep_kernel<<<(DIM * NTREES) / 256 + 1, 256, 0, stream>>>(fsl, thr, lt, selp, thrp);
        gemm_gates<<<dim3(NB, MB), 128, 0, stream>>>(x, selp, thrp, gates);
        tree_kernel<<<NTG * 8, 256, 0, stream>>>(gates, resp, partial);
        reduce_kernel<<<(BATCH * UNITS) / 256, 256, 0, stream>>>(partial, out, NTG);
    } else {
        // ---------- fallback: round-2 proven fused path (~7.4 MB ws) ----------
        float* selp    = ws + FB_SELP;
        float* thrp    = ws + FB_THRP;
        float* partial = ws + FB_PARTIAL;

        prep_kernel<<<(DIM * NTREES) / 256 + 1, 256, 0, stream>>>(fsl, thr, lt, selp, thrp);
        fused_kernel<<<dim3(FBNT, FBBB), 256, 0, stream>>>(x, selp, thrp, resp, partial);
        reduce_kernel<<<(BATCH * UNITS) / 256, 256, 0, stream>>>(partial, out, FBNT);
    }
}